// Round 8
// baseline (226.752 us; speedup 1.0000x reference)
//
#include <hip/hip_runtime.h>
#include <math.h>

#define BB   8
#define NN   1024
#define SS   128
#define KK   32
#define EMB  384

// padded K strides (elements) for transposed split weights
#define KP1  136   // W1bt [256][136]
#define KP2  264   // W2at [512][264]
#define KP3  520   // W2bt [384][520]

typedef __attribute__((ext_vector_type(4))) float f32x4;
typedef __attribute__((ext_vector_type(8))) short s16x8;

__device__ __forceinline__ unsigned short f2bf(float x) {
    unsigned u = __float_as_uint(x);
    unsigned r = (u + 0x7FFFu + ((u >> 16) & 1u)) >> 16;   // RN-even
    return (unsigned short)r;
}
__device__ __forceinline__ float bf2f(unsigned short h) {
    return __uint_as_float(((unsigned)h) << 16);
}
__device__ __forceinline__ f32x4 mfma16(s16x8 a, s16x8 b, f32x4 c) {
    return __builtin_amdgcn_mfma_f32_16x16x32_bf16(a, b, c, 0, 0, 0);
}

// ---------------------------------------------------------------------------
// pre_kernel: blocks 0..7 = FPS (verified round 7: LDS broadcast-read argmax);
// blocks 8..359 = weight transpose + bf16 hi/lo split.
// ---------------------------------------------------------------------------
__global__ __launch_bounds__(256) void pre_kernel(
    const float* __restrict__ pos, float* __restrict__ seed_pos,
    const float* __restrict__ W1b, const float* __restrict__ W2a,
    const float* __restrict__ W2b,
    unsigned short* __restrict__ W1bt_h, unsigned short* __restrict__ W1bt_l,
    unsigned short* __restrict__ W2at_h, unsigned short* __restrict__ W2at_l,
    unsigned short* __restrict__ W2bt_h, unsigned short* __restrict__ W2bt_l)
{
    __shared__ float s_cloud[3][NN];             // FPS path (12 KB)
    __shared__ __align__(16) float s_red[64];    // FPS reduce slots
    __shared__ float tile[32][33];               // prep path
    const int bid = blockIdx.x;
    if (bid < BB) {
        // ---------------- FPS ----------------
        const int b = bid;
        const float* p = pos + (size_t)b * NN * 3;
        for (int k = 0; k < 4; ++k) {
            const int i = threadIdx.x + k * 256;
            s_cloud[0][i] = p[i * 3 + 0];
            s_cloud[1][i] = p[i * 3 + 1];
            s_cloud[2][i] = p[i * 3 + 2];
        }
        __syncthreads();
        if (threadIdx.x >= 64) return;           // single wave from here on
        const int l = threadIdx.x;

        float px[16], py[16], pz[16], mind[16];
#pragma unroll
        for (int r = 0; r < 16; ++r) {
            const int i = r * 64 + l;
            px[r] = s_cloud[0][i];
            py[r] = s_cloud[1][i];
            pz[r] = s_cloud[2][i];
            mind[r] = INFINITY;
        }

        int gi = 0;                              // current seed idx (uniform)
        for (int s = 0; s < SS; ++s) {
            const float sxv = s_cloud[0][gi];
            const float syv = s_cloud[1][gi];
            const float szv = s_cloud[2][gi];
            if (l == 0) {
                seed_pos[((size_t)b * SS + s) * 3 + 0] = sxv;
                seed_pos[((size_t)b * SS + s) * 3 + 1] = syv;
                seed_pos[((size_t)b * SS + s) * 3 + 2] = szv;
            }
            if (s == SS - 1) break;
            // exact np-order distance: ((dx*dx + dy*dy) + dz*dz), no FMA
#pragma unroll
            for (int r = 0; r < 16; ++r) {
                const float dx = __fsub_rn(px[r], sxv);
                const float dy = __fsub_rn(py[r], syv);
                const float dz = __fsub_rn(pz[r], szv);
                const float d = __fadd_rn(__fadd_rn(__fmul_rn(dx, dx), __fmul_rn(dy, dy)),
                                          __fmul_rn(dz, dz));
                mind[r] = fminf(mind[r], d);
            }
            // local max over 16 regs: pairwise VALU tree (value only)
            float t8[8];
#pragma unroll
            for (int r = 0; r < 8; ++r) t8[r] = fmaxf(mind[r], mind[r + 8]);
            float t4a = fmaxf(t8[0], t8[4]), t4b = fmaxf(t8[1], t8[5]);
            float t4c = fmaxf(t8[2], t8[6]), t4d = fmaxf(t8[3], t8[7]);
            const float lm = fmaxf(fmaxf(t4a, t4b), fmaxf(t4c, t4d));

            s_red[l] = lm;                       // one ds_write_b32 per lane
            // broadcast reads: 16 x ds_read_b128, identical addr across lanes
            const f32x4* rp = (const f32x4*)s_red;
            f32x4 acc = rp[0];
#pragma unroll
            for (int i = 1; i < 16; ++i) {
                const f32x4 v = rp[i];
                acc.x = fmaxf(acc.x, v.x);
                acc.y = fmaxf(acc.y, v.y);
                acc.z = fmaxf(acc.z, v.z);
                acc.w = fmaxf(acc.w, v.w);
            }
            const float gmax = fmaxf(fmaxf(acc.x, acc.y), fmaxf(acc.z, acc.w));

            // local lowest idx matching gmax (descending -> lowest r wins)
            int bl = 0x7fffffff;
#pragma unroll
            for (int r = 15; r >= 0; --r) {
                bl = (mind[r] == gmax) ? (r * 64 + l) : bl;
            }
            unsigned long long mball = __ballot(bl != 0x7fffffff);
            int best = 0x7fffffff;
            while (mball) {                      // wave-uniform; expected 1 iter
                const int ln = (int)__ffsll(mball) - 1;
                const int cand = __builtin_amdgcn_readlane(bl, ln);
                best = cand < best ? cand : best;
                mball &= (mball - 1);
            }
            gi = best;
        }
        return;
    }

    // ---------------- weight prep: 32x32 tile transpose + split ----------------
    int tid = bid - BB;
    const float* src;
    unsigned short *dh, *dl;
    int N, Kp, koff, kt, nt;
    if (tid < 32) {
        src = W1b; dh = W1bt_h; dl = W1bt_l; N = 256; Kp = KP1; koff = 0;
        kt = tid >> 3; nt = tid & 7;
    } else if (tid < 160) {
        tid -= 32;
        src = W2a; dh = W2at_h; dl = W2at_l; N = 512; Kp = KP2; koff = 256;
        kt = tid >> 4; nt = tid & 15;
    } else {
        tid -= 160;
        src = W2b; dh = W2bt_h; dl = W2bt_l; N = 384; Kp = KP3; koff = 0;
        kt = tid / 12; nt = tid % 12;
    }
    const int k0 = kt * 32, n0 = nt * 32;
    const int tx = threadIdx.x & 31, ty = threadIdx.x >> 5;
#pragma unroll
    for (int i = 0; i < 4; ++i) {
        const int kl = ty + i * 8;
        tile[kl][tx] = src[(size_t)(k0 + kl + koff) * N + n0 + tx];
    }
    __syncthreads();
#pragma unroll
    for (int i = 0; i < 4; ++i) {
        const int nl = ty + i * 8;
        const float x = tile[tx][nl];
        const unsigned short hi = f2bf(x);
        const unsigned short lo = f2bf(x - bf2f(hi));
        const size_t o = (size_t)(n0 + nl) * Kp + k0 + tx;
        dh[o] = hi;
        dl[o] = lo;
    }
}

// ---------------------------------------------------------------------------
// kNN: wave-per-seed, shfl butterfly argmin (verified rounds 3-4, 7).
// ---------------------------------------------------------------------------
__global__ __launch_bounds__(512) void knn_kernel(
    const float* __restrict__ pos,
    const float* __restrict__ seed_pos,
    int* __restrict__ nbr)
{
    __shared__ float sx_[NN], sy_[NN], sz_[NN];
    const int blk = blockIdx.x;            // 0..127
    const int b   = blk >> 4;
    const int t   = threadIdx.x;
    const int w   = t >> 6;
    const int l   = t & 63;
    const float* p = pos + (size_t)b * NN * 3;

    for (int i = t; i < NN; i += 512) {
        sx_[i] = p[i * 3 + 0];
        sy_[i] = p[i * 3 + 1];
        sz_[i] = p[i * 3 + 2];
    }
    __syncthreads();

    const int gsid = b * SS + (blk & 15) * 8 + w;
    const float cx = seed_pos[gsid * 3 + 0];
    const float cy = seed_pos[gsid * 3 + 1];
    const float cz = seed_pos[gsid * 3 + 2];

    float d[16];
#pragma unroll
    for (int r = 0; r < 16; ++r) {
        const int i = r * 64 + l;
        const float dx = __fsub_rn(sx_[i], cx);
        const float dy = __fsub_rn(sy_[i], cy);
        const float dz = __fsub_rn(sz_[i], cz);
        d[r] = __fadd_rn(__fadd_rn(__fmul_rn(dx, dx), __fmul_rn(dy, dy)),
                         __fmul_rn(dz, dz));
    }

    for (int it = 0; it < KK; ++it) {
        float best = INFINITY;
        int bi = NN;
#pragma unroll
        for (int r = 0; r < 16; ++r) {
            if (d[r] < best) { best = d[r]; bi = r * 64 + l; }
        }
#pragma unroll
        for (int off = 1; off < 64; off <<= 1) {
            const float ov = __shfl_xor(best, off);
            const int   oi = __shfl_xor(bi, off);
            if (ov < best || (ov == best && oi < bi)) { best = ov; bi = oi; }
        }
        const int wr = bi >> 6, wl = bi & 63;
#pragma unroll
        for (int r = 0; r < 16; ++r) {
            if (r == wr && l == wl) d[r] = INFINITY;
        }
        if (l == 0) nbr[(size_t)gsid * KK + it] = bi;
    }
}

// ---------------------------------------------------------------------------
// PointConv, M=64 (2 seeds/block), 8 waves, 2 blocks/CU (LDS 72,448 B).
// Region map:
//   R0 [0,32768):      H1 hi/lo ([64][256B] each) -> A2 half1 -> A3 hi ([64][512B])
//   R1 [32768,65536):  A2 half0 (hi/lo [64][256B]) -> A3 lo
//   s_g [2][256] @65536 ; s_base [2][512] @67584 ; s_rel [64][3] @71680
// A2 halves: cols 0..127 -> R1 (waves 0-3 own them), cols 128..255 -> R0
// (waves 4-7). Extra barrier between GEMM1 (reads R0) and A2 writes (to R0).
// GEMM2 reads R1 for ksteps 0-3, R0 for 4-7. GEMM3 identical to round 7.
// ---------------------------------------------------------------------------
__global__ __launch_bounds__(512, 4) void conv_kernel(
    const float* __restrict__ pos,
    const float* __restrict__ seed_pos,
    const int* __restrict__ nbr,
    const float* __restrict__ W1a, const float* __restrict__ b1a,
    const float* __restrict__ b1b,
    const float* __restrict__ W2a, const float* __restrict__ b2a,
    const float* __restrict__ b2b,
    const unsigned short* __restrict__ W1bt_h, const unsigned short* __restrict__ W1bt_l,
    const unsigned short* __restrict__ W2at_h, const unsigned short* __restrict__ W2at_l,
    const unsigned short* __restrict__ W2bt_h, const unsigned short* __restrict__ W2bt_l,
    float* __restrict__ out)
{
    __shared__ __align__(16) unsigned char smem[72448];
    unsigned char* sR0  = smem;                // 32KB region 0
    unsigned char* sR1  = smem + 32768;        // 32KB region 1
    unsigned char* sH1h = sR0;                 // [64][256B]
    unsigned char* sH1l = sR0 + 16384;         // [64][256B]
    unsigned char* sA3h = sR0;                 // [64][512B] (GEMM3 A hi)
    unsigned char* sA3l = sR1;                 // [64][512B] (GEMM3 A lo)
    float* s_g    = (float*)(smem + 65536);    // [2][256]
    float* s_base = (float*)(smem + 67584);    // [2][512]
    float* s_rel  = (float*)(smem + 71680);    // [64][3]

    const int blk = blockIdx.x;                // seeds blk*2, blk*2+1
    const int t   = threadIdx.x;
    const int w   = t >> 6;
    const int l   = t & 63;
    const int lg  = l >> 4;
    const int l15 = l & 15;

    // ---- stage 0: gather rel for 64 rows (2 seeds x 32 neighbors) ----
    if (t < 64) {
        const int sl   = t >> 5;
        const int gsid = blk * 2 + sl;
        const int b    = gsid >> 7;
        const int pi   = nbr[(size_t)gsid * KK + (t & 31)];
        const float* pp = pos + ((size_t)b * NN + pi) * 3;
        s_rel[t * 3 + 0] = pp[0] - seed_pos[gsid * 3 + 0];
        s_rel[t * 3 + 1] = pp[1] - seed_pos[gsid * 3 + 1];
        s_rel[t * 3 + 2] = pp[2] - seed_pos[gsid * 3 + 2];
    }
    __syncthreads();

    // ---- stage 1: h1[64][128] = relu(rel@W1a + b1a) -> H1 hi/lo swizzled ----
    {
        const int j  = t & 127;
        const int rg = t >> 7;
        const float w0 = W1a[j], w1 = W1a[128 + j], w2 = W1a[256 + j], bb = b1a[j];
#pragma unroll
        for (int rr = 0; rr < 16; ++rr) {
            const int row = rg * 16 + rr;
            float v = fmaf(s_rel[row * 3 + 2], w2,
                      fmaf(s_rel[row * 3 + 1], w1,
                      fmaf(s_rel[row * 3 + 0], w0, bb)));
            v = fmaxf(v, 0.0f);
            const unsigned short hi = f2bf(v);
            const unsigned short lo = f2bf(v - bf2f(hi));
            const int byte = (j * 2) ^ ((row & 7) << 4);
            *(unsigned short*)(sH1h + row * 256 + byte) = hi;
            *(unsigned short*)(sH1l + row * 256 + byte) = lo;
        }
    }
    __syncthreads();

    // ---- GEMM1: f = h1 @ W1b (M=64,N=256,K=128); C1 kept in regs ----
    f32x4 C1[4][2];
#pragma unroll
    for (int m = 0; m < 4; ++m)
#pragma unroll
        for (int i = 0; i < 2; ++i) C1[m][i] = (f32x4){0.f, 0.f, 0.f, 0.f};
#pragma unroll
    for (int ks = 0; ks < 4; ++ks) {
        s16x8 ah[4], al[4], bh[2], bl[2];
#pragma unroll
        for (int m = 0; m < 4; ++m) {
            const int row = m * 16 + l15;
            const int byte = (lg * 16 + ks * 64) ^ ((row & 7) << 4);
            ah[m] = *(const s16x8*)(sH1h + row * 256 + byte);
            al[m] = *(const s16x8*)(sH1l + row * 256 + byte);
        }
#pragma unroll
        for (int i = 0; i < 2; ++i) {
            const int ncol = w * 32 + i * 16 + l15;
            const size_t off = (size_t)ncol * KP1 + lg * 8 + ks * 32;
            bh[i] = *(const s16x8*)(W1bt_h + off);
            bl[i] = *(const s16x8*)(W1bt_l + off);
        }
#pragma unroll
        for (int i = 0; i < 2; ++i)
#pragma unroll
            for (int m = 0; m < 4; ++m) C1[m][i] = mfma16(ah[m], bh[i], C1[m][i]);
#pragma unroll
        for (int i = 0; i < 2; ++i)
#pragma unroll
            for (int m = 0; m < 4; ++m) C1[m][i] = mfma16(ah[m], bl[i], C1[m][i]);
#pragma unroll
        for (int i = 0; i < 2; ++i)
#pragma unroll
            for (int m = 0; m < 4; ++m) C1[m][i] = mfma16(al[m], bh[i], C1[m][i]);
    }
    // colmax -> s_g (pre-barrier; C1 retained for the A2 write after barrier)
#pragma unroll
    for (int i = 0; i < 2; ++i) {
        const int col = w * 32 + i * 16 + l15;
        const float bias = b1b[col];
        float pm0 = -INFINITY, pm1 = -INFINITY;
#pragma unroll
        for (int m = 0; m < 4; ++m)
#pragma unroll
            for (int r = 0; r < 4; ++r) {
                const float v = C1[m][i][r] + bias;
                if (m < 2) pm0 = fmaxf(pm0, v); else pm1 = fmaxf(pm1, v);
            }
        pm0 = fmaxf(pm0, __shfl_xor(pm0, 16));
        pm0 = fmaxf(pm0, __shfl_xor(pm0, 32));
        pm1 = fmaxf(pm1, __shfl_xor(pm1, 16));
        pm1 = fmaxf(pm1, __shfl_xor(pm1, 32));
        if (lg == 0) { s_g[col] = pm0; s_g[256 + col] = pm1; }
    }
    __syncthreads();   // all H1 (R0) reads done; s_g complete

    // ---- A2 write: cols<128 -> R1, cols>=128 -> R0 (overwrites dead H1) ----
#pragma unroll
    for (int i = 0; i < 2; ++i) {
        const int col = w * 32 + i * 16 + l15;
        const float bias = b1b[col];
        unsigned char* reg = (col < 128) ? sR1 : sR0;   // wave-uniform
        const int colL = col & 127;
#pragma unroll
        for (int m = 0; m < 4; ++m)
#pragma unroll
            for (int r = 0; r < 4; ++r) {
                const float v = C1[m][i][r] + bias;
                const int row = m * 16 + lg * 4 + r;
                const unsigned short hi = f2bf(v);
                const unsigned short lo = f2bf(v - bf2f(hi));
                const int byte = (colL * 2) ^ ((row & 7) << 4);
                *(unsigned short*)(reg + row * 256 + byte) = hi;
                *(unsigned short*)(reg + 16384 + row * 256 + byte) = lo;
            }
    }

    // ---- base[seed][c] = b2a[c] + g_seed @ W2a[0:256] ----
    {
        const int c = t;
        float a0 = b2a[c], a1 = b2a[c];
#pragma unroll 4
        for (int jj = 0; jj < 256; ++jj) {
            const float w_ = W2a[(size_t)jj * 512 + c];
            a0 = fmaf(s_g[jj],       w_, a0);
            a1 = fmaf(s_g[256 + jj], w_, a1);
        }
        s_base[c] = a0;
        s_base[512 + c] = a1;
    }
    __syncthreads();   // A2 halves + s_base complete

    // ---- GEMM2: C2 = f @ W2a[256:] (M=64,N=512,K=256) ----
    f32x4 C2[4][4];
#pragma unroll
    for (int m = 0; m < 4; ++m)
#pragma unroll
        for (int n = 0; n < 4; ++n) C2[m][n] = (f32x4){0.f, 0.f, 0.f, 0.f};
#pragma unroll 2
    for (int ks = 0; ks < 8; ++ks) {
        const unsigned char* areg = (ks < 4) ? sR1 : sR0;   // uniform select
        const int kb = (ks & 3) * 64;
        s16x8 ah[4], al[4];
#pragma unroll
        for (int m = 0; m < 4; ++m) {
            const int row = m * 16 + l15;
            const int byte = (lg * 16 + kb) ^ ((row & 7) << 4);
            ah[m] = *(const s16x8*)(areg + row * 256 + byte);
            al[m] = *(const s16x8*)(areg + 16384 + row * 256 + byte);
        }
#pragma unroll
        for (int n = 0; n < 4; ++n) {
            const int ncol = n * 128 + w * 16 + l15;
            const size_t off = (size_t)ncol * KP2 + lg * 8 + ks * 32;
            const s16x8 bh = *(const s16x8*)(W2at_h + off);
            const s16x8 bl = *(const s16x8*)(W2at_l + off);
#pragma unroll
            for (int m = 0; m < 4; ++m) C2[m][n] = mfma16(ah[m], bh, C2[m][n]);
#pragma unroll
            for (int m = 0; m < 4; ++m) C2[m][n] = mfma16(ah[m], bl, C2[m][n]);
#pragma unroll
            for (int m = 0; m < 4; ++m) C2[m][n] = mfma16(al[m], bh, C2[m][n]);
        }
    }
    __syncthreads();   // A2 (R0/R1) fully read; A3 staging may overwrite

    // ---- GEMM3: e = h2 @ W2b, K-split; A3 hi->R0, lo->R1 ([64][512B]) ----
    f32x4 C3[4][3];
#pragma unroll
    for (int m = 0; m < 4; ++m)
#pragma unroll
        for (int n = 0; n < 3; ++n) C3[m][n] = (f32x4){0.f, 0.f, 0.f, 0.f};

#pragma unroll
    for (int h = 0; h < 2; ++h) {
        // write phase: h2 cols [h*256, h*256+256) = relu(C2 + base)
#pragma unroll
        for (int q = 0; q < 2; ++q) {
            const int n = 2 * h + q;
            const int col  = n * 128 + w * 16 + l15;
            const int colL = q * 128 + w * 16 + l15;
            const float bs0 = s_base[col];
            const float bs1 = s_base[512 + col];
#pragma unroll
            for (int m = 0; m < 4; ++m)
#pragma unroll
                for (int r = 0; r < 4; ++r) {
                    const float v = fmaxf(C2[m][n][r] + (m < 2 ? bs0 : bs1), 0.0f);
                    const int row = m * 16 + lg * 4 + r;
                    const unsigned short hi = f2bf(v);
                    const unsigned short lo = f2bf(v - bf2f(hi));
                    const int byte = (colL * 2) ^ ((row & 7) << 4);
                    *(unsigned short*)(sA3h + row * 512 + byte) = hi;
                    *(unsigned short*)(sA3l + row * 512 + byte) = lo;
                }
        }
        __syncthreads();

        const int koff = h * 256;
#pragma unroll 2
        for (int ks = 0; ks < 8; ++ks) {
            s16x8 ah[4], al[4];
#pragma unroll
            for (int m = 0; m < 4; ++m) {
                const int row = m * 16 + l15;
                const int byte = (lg * 16 + ks * 64) ^ ((row & 7) << 4);
                ah[m] = *(const s16x8*)(sA3h + row * 512 + byte);
                al[m] = *(const s16x8*)(sA3l + row * 512 + byte);
            }
#pragma unroll
            for (int n = 0; n < 3; ++n) {
                const int ncol = w * 48 + n * 16 + l15;
                const size_t off = (size_t)ncol * KP3 + koff + lg * 8 + ks * 32;
                const s16x8 bh = *(const s16x8*)(W2bt_h + off);
                const s16x8 bl = *(const s16x8*)(W2bt_l + off);
#pragma unroll
                for (int m = 0; m < 4; ++m) C3[m][n] = mfma16(ah[m], bh, C3[m][n]);
#pragma unroll
                for (int m = 0; m < 4; ++m) C3[m][n] = mfma16(ah[m], bl, C3[m][n]);
#pragma unroll
                for (int m = 0; m < 4; ++m) C3[m][n] = mfma16(al[m], bh, C3[m][n]);
            }
        }
        if (h == 0) __syncthreads();   // A3 buffers rewritten next h
    }

    // ---- epilogue: out[seed] = colmax(e_seed) + b2b ----
#pragma unroll
    for (int n = 0; n < 3; ++n) {
        const int col = w * 48 + n * 16 + l15;
        float pm0 = -INFINITY, pm1 = -INFINITY;
#pragma unroll
        for (int m = 0; m < 4; ++m)
#pragma unroll
            for (int r = 0; r < 4; ++r) {
                if (m < 2) pm0 = fmaxf(pm0, C3[m][n][r]);
                else       pm1 = fmaxf(pm1, C3[m][n][r]);
            }
        pm0 = fmaxf(pm0, __shfl_xor(pm0, 16));
        pm0 = fmaxf(pm0, __shfl_xor(pm0, 32));
        pm1 = fmaxf(pm1, __shfl_xor(pm1, 16));
        pm1 = fmaxf(pm1, __shfl_xor(pm1, 32));
        if (lg == 0) {
            out[(size_t)(blk * 2 + 0) * EMB + col] = pm0 + b2b[col];
            out[(size_t)(blk * 2 + 1) * EMB + col] = pm1 + b2b[col];
        }
    }
}

// ---------------------------------------------------------------------------
extern "C" void kernel_launch(void* const* d_in, const int* in_sizes, int n_in,
                              void* d_out, int out_size, void* d_ws, size_t ws_size,
                              hipStream_t stream)
{
    const float* pos = (const float*)d_in[0];
    const float* W1a = (const float*)d_in[2];
    const float* b1a = (const float*)d_in[3];
    const float* W1b = (const float*)d_in[4];
    const float* b1b = (const float*)d_in[5];
    const float* W2a = (const float*)d_in[6];
    const float* b2a = (const float*)d_in[7];
    const float* W2b = (const float*)d_in[8];
    const float* b2b = (const float*)d_in[9];
    float* out = (float*)d_out;

    unsigned char* ws = (unsigned char*)d_ws;
    float* seed_pos = (float*)(ws + 0);                         // 12 KB
    int*   nbr      = (int*)(ws + 16384);                       // 128 KB
    unsigned short* W1bt_h = (unsigned short*)(ws + 147456);    // [256][136]
    unsigned short* W1bt_l = (unsigned short*)(ws + 217088);
    unsigned short* W2at_h = (unsigned short*)(ws + 286720);    // [512][264]
    unsigned short* W2at_l = (unsigned short*)(ws + 557056);
    unsigned short* W2bt_h = (unsigned short*)(ws + 827392);    // [384][520]
    unsigned short* W2bt_l = (unsigned short*)(ws + 1226752);

    pre_kernel<<<BB + 352, 256, 0, stream>>>(pos, seed_pos, W1b, W2a, W2b,
                                             W1bt_h, W1bt_l, W2at_h, W2at_l,
                                             W2bt_h, W2bt_l);
    knn_kernel<<<BB * SS / 8, 512, 0, stream>>>(pos, seed_pos, nbr);
    conv_kernel<<<BB * SS / 2, 512, 0, stream>>>(pos, seed_pos, nbr,
                                                 W1a, b1a, b1b, W2a, b2a, b2b,
                                                 W1bt_h, W1bt_l, W2at_h, W2at_l,
                                                 W2bt_h, W2bt_l, out);
}

// Round 9
// 169.208 us; speedup vs baseline: 1.3401x; 1.3401x over previous
//
#include <hip/hip_runtime.h>
#include <math.h>

#define BB   8
#define NN   1024
#define SS   128
#define KK   32
#define EMB  384

// padded K strides (elements) for transposed f16 weights
#define KP1  136   // W1bt [256][136]
#define KP2  264   // W2at [512][264]
#define KP3  520   // W2bt [384][520]

typedef __attribute__((ext_vector_type(4))) float f32x4;
typedef __attribute__((ext_vector_type(8))) _Float16 f16x8;

__device__ __forceinline__ f32x4 mfma16h(f16x8 a, f16x8 b, f32x4 c) {
    return __builtin_amdgcn_mfma_f32_16x16x32_f16(a, b, c, 0, 0, 0);
}

// ---------------------------------------------------------------------------
// pre_kernel: blocks 0..7 = FPS (verified round 7: LDS broadcast-read argmax);
// blocks 8..359 = weight transpose + f16 convert (single table, no lo-split).
// ---------------------------------------------------------------------------
__global__ __launch_bounds__(256) void pre_kernel(
    const float* __restrict__ pos, float* __restrict__ seed_pos,
    const float* __restrict__ W1b, const float* __restrict__ W2a,
    const float* __restrict__ W2b,
    _Float16* __restrict__ W1bt, _Float16* __restrict__ W2at,
    _Float16* __restrict__ W2bt)
{
    __shared__ float s_cloud[3][NN];             // FPS path (12 KB)
    __shared__ __align__(16) float s_red[64];    // FPS reduce slots
    __shared__ float tile[32][33];               // prep path
    const int bid = blockIdx.x;
    if (bid < BB) {
        // ---------------- FPS ----------------
        const int b = bid;
        const float* p = pos + (size_t)b * NN * 3;
        for (int k = 0; k < 4; ++k) {
            const int i = threadIdx.x + k * 256;
            s_cloud[0][i] = p[i * 3 + 0];
            s_cloud[1][i] = p[i * 3 + 1];
            s_cloud[2][i] = p[i * 3 + 2];
        }
        __syncthreads();
        if (threadIdx.x >= 64) return;           // single wave from here on
        const int l = threadIdx.x;

        float px[16], py[16], pz[16], mind[16];
#pragma unroll
        for (int r = 0; r < 16; ++r) {
            const int i = r * 64 + l;
            px[r] = s_cloud[0][i];
            py[r] = s_cloud[1][i];
            pz[r] = s_cloud[2][i];
            mind[r] = INFINITY;
        }

        int gi = 0;                              // current seed idx (uniform)
        for (int s = 0; s < SS; ++s) {
            const float sxv = s_cloud[0][gi];
            const float syv = s_cloud[1][gi];
            const float szv = s_cloud[2][gi];
            if (l == 0) {
                seed_pos[((size_t)b * SS + s) * 3 + 0] = sxv;
                seed_pos[((size_t)b * SS + s) * 3 + 1] = syv;
                seed_pos[((size_t)b * SS + s) * 3 + 2] = szv;
            }
            if (s == SS - 1) break;
#pragma unroll
            for (int r = 0; r < 16; ++r) {
                const float dx = __fsub_rn(px[r], sxv);
                const float dy = __fsub_rn(py[r], syv);
                const float dz = __fsub_rn(pz[r], szv);
                const float d = __fadd_rn(__fadd_rn(__fmul_rn(dx, dx), __fmul_rn(dy, dy)),
                                          __fmul_rn(dz, dz));
                mind[r] = fminf(mind[r], d);
            }
            float t8[8];
#pragma unroll
            for (int r = 0; r < 8; ++r) t8[r] = fmaxf(mind[r], mind[r + 8]);
            float t4a = fmaxf(t8[0], t8[4]), t4b = fmaxf(t8[1], t8[5]);
            float t4c = fmaxf(t8[2], t8[6]), t4d = fmaxf(t8[3], t8[7]);
            const float lm = fmaxf(fmaxf(t4a, t4b), fmaxf(t4c, t4d));

            s_red[l] = lm;
            const f32x4* rp = (const f32x4*)s_red;
            f32x4 acc = rp[0];
#pragma unroll
            for (int i = 1; i < 16; ++i) {
                const f32x4 v = rp[i];
                acc.x = fmaxf(acc.x, v.x);
                acc.y = fmaxf(acc.y, v.y);
                acc.z = fmaxf(acc.z, v.z);
                acc.w = fmaxf(acc.w, v.w);
            }
            const float gmax = fmaxf(fmaxf(acc.x, acc.y), fmaxf(acc.z, acc.w));

            int bl = 0x7fffffff;
#pragma unroll
            for (int r = 15; r >= 0; --r) {
                bl = (mind[r] == gmax) ? (r * 64 + l) : bl;
            }
            unsigned long long mball = __ballot(bl != 0x7fffffff);
            int best = 0x7fffffff;
            while (mball) {
                const int ln = (int)__ffsll(mball) - 1;
                const int cand = __builtin_amdgcn_readlane(bl, ln);
                best = cand < best ? cand : best;
                mball &= (mball - 1);
            }
            gi = best;
        }
        return;
    }

    // ---------------- weight prep: 32x32 tile transpose + f16 convert --------
    int tid = bid - BB;
    const float* src;
    _Float16* dh;
    int N, Kp, koff, kt, nt;
    if (tid < 32) {
        src = W1b; dh = W1bt; N = 256; Kp = KP1; koff = 0;
        kt = tid >> 3; nt = tid & 7;
    } else if (tid < 160) {
        tid -= 32;
        src = W2a; dh = W2at; N = 512; Kp = KP2; koff = 256;
        kt = tid >> 4; nt = tid & 15;
    } else {
        tid -= 160;
        src = W2b; dh = W2bt; N = 384; Kp = KP3; koff = 0;
        kt = tid / 12; nt = tid % 12;
    }
    const int k0 = kt * 32, n0 = nt * 32;
    const int tx = threadIdx.x & 31, ty = threadIdx.x >> 5;
#pragma unroll
    for (int i = 0; i < 4; ++i) {
        const int kl = ty + i * 8;
        tile[kl][tx] = src[(size_t)(k0 + kl + koff) * N + n0 + tx];
    }
    __syncthreads();
#pragma unroll
    for (int i = 0; i < 4; ++i) {
        const int nl = ty + i * 8;
        dh[(size_t)(n0 + nl) * Kp + k0 + tx] = (_Float16)tile[tx][nl];
    }
}

// ---------------------------------------------------------------------------
// kNN: wave-per-seed, shfl butterfly argmin (verified rounds 3-4, 7-8).
// ---------------------------------------------------------------------------
__global__ __launch_bounds__(512) void knn_kernel(
    const float* __restrict__ pos,
    const float* __restrict__ seed_pos,
    int* __restrict__ nbr)
{
    __shared__ float sx_[NN], sy_[NN], sz_[NN];
    const int blk = blockIdx.x;            // 0..127
    const int b   = blk >> 4;
    const int t   = threadIdx.x;
    const int w   = t >> 6;
    const int l   = t & 63;
    const float* p = pos + (size_t)b * NN * 3;

    for (int i = t; i < NN; i += 512) {
        sx_[i] = p[i * 3 + 0];
        sy_[i] = p[i * 3 + 1];
        sz_[i] = p[i * 3 + 2];
    }
    __syncthreads();

    const int gsid = b * SS + (blk & 15) * 8 + w;
    const float cx = seed_pos[gsid * 3 + 0];
    const float cy = seed_pos[gsid * 3 + 1];
    const float cz = seed_pos[gsid * 3 + 2];

    float d[16];
#pragma unroll
    for (int r = 0; r < 16; ++r) {
        const int i = r * 64 + l;
        const float dx = __fsub_rn(sx_[i], cx);
        const float dy = __fsub_rn(sy_[i], cy);
        const float dz = __fsub_rn(sz_[i], cz);
        d[r] = __fadd_rn(__fadd_rn(__fmul_rn(dx, dx), __fmul_rn(dy, dy)),
                         __fmul_rn(dz, dz));
    }

    for (int it = 0; it < KK; ++it) {
        float best = INFINITY;
        int bi = NN;
#pragma unroll
        for (int r = 0; r < 16; ++r) {
            if (d[r] < best) { best = d[r]; bi = r * 64 + l; }
        }
#pragma unroll
        for (int off = 1; off < 64; off <<= 1) {
            const float ov = __shfl_xor(best, off);
            const int   oi = __shfl_xor(bi, off);
            if (ov < best || (ov == best && oi < bi)) { best = ov; bi = oi; }
        }
        const int wr = bi >> 6, wl = bi & 63;
#pragma unroll
        for (int r = 0; r < 16; ++r) {
            if (r == wr && l == wl) d[r] = INFINITY;
        }
        if (l == 0) nbr[(size_t)gsid * KK + it] = bi;
    }
}

// ---------------------------------------------------------------------------
// PointConv, M=128 (4 seeds/block), 1024 threads = 16 waves, f16 operands.
// N-only wave partition -> every weight element read ONCE per block.
// LDS (144,896 B), one rotating 128 KB region:
//   phase1: h1 f16 [128 rows][256B]   @[0,32768)
//   phase2: A2 f16 [128][512B]        @[0,65536)   (h1 dead)
//   phase3: A3 f16 [128][1024B]       @[0,131072)  (A2 dead)
//   s_g f32 [4][256] @131072 ; s_base f32 [4][512] @135168 ; s_rel @143360
// Full A2/A3 staged -> GEMM2/GEMM3 have no K-split phases, no mid barriers.
// GEMM3 runs on waves 0-11 (12 x 32 cols = 384). VGPR peak ~90 (<128 @16 waves).
// ---------------------------------------------------------------------------
__global__ __launch_bounds__(1024) void conv_kernel(
    const float* __restrict__ pos,
    const float* __restrict__ seed_pos,
    const int* __restrict__ nbr,
    const float* __restrict__ W1a, const float* __restrict__ b1a,
    const float* __restrict__ b1b,
    const float* __restrict__ W2a, const float* __restrict__ b2a,
    const float* __restrict__ b2b,
    const _Float16* __restrict__ W1bt, const _Float16* __restrict__ W2at,
    const _Float16* __restrict__ W2bt,
    float* __restrict__ out)
{
    __shared__ __align__(16) unsigned char smem[144896];
    unsigned char* sBig = smem;                 // rotating region
    float* s_g    = (float*)(smem + 131072);    // [4][256]
    float* s_base = (float*)(smem + 135168);    // [4][512]
    float* s_rel  = (float*)(smem + 143360);    // [128][3]

    const int blk = blockIdx.x;                 // seeds blk*4 .. blk*4+3
    const int t   = threadIdx.x;
    const int w   = t >> 6;                     // wave 0..15
    const int l   = t & 63;
    const int lg  = l >> 4;
    const int l15 = l & 15;

    // ---- stage 0: gather rel for 128 rows (4 seeds x 32 neighbors) ----
    if (t < 128) {
        const int sl   = t >> 5;
        const int gsid = blk * 4 + sl;
        const int b    = gsid >> 7;
        const int pi   = nbr[(size_t)gsid * KK + (t & 31)];
        const float* pp = pos + ((size_t)b * NN + pi) * 3;
        s_rel[t * 3 + 0] = pp[0] - seed_pos[gsid * 3 + 0];
        s_rel[t * 3 + 1] = pp[1] - seed_pos[gsid * 3 + 1];
        s_rel[t * 3 + 2] = pp[2] - seed_pos[gsid * 3 + 2];
    }
    __syncthreads();

    // ---- stage 1: h1[128][128] = relu(rel@W1a + b1a) -> f16 swizzled ----
    {
        const int j  = t & 127;
        const int rg = t >> 7;                  // 0..7, 16 rows each
        const float w0 = W1a[j], w1 = W1a[128 + j], w2 = W1a[256 + j], bb = b1a[j];
#pragma unroll
        for (int rr = 0; rr < 16; ++rr) {
            const int row = rg * 16 + rr;
            float v = fmaf(s_rel[row * 3 + 2], w2,
                      fmaf(s_rel[row * 3 + 1], w1,
                      fmaf(s_rel[row * 3 + 0], w0, bb)));
            v = fmaxf(v, 0.0f);
            const int byte = (j * 2) ^ ((row & 7) << 4);
            *(_Float16*)(sBig + row * 256 + byte) = (_Float16)v;
        }
    }
    __syncthreads();

    // ---- GEMM1: f = h1 @ W1b (M=128,N=256,K=128); wave w owns cols w*16+ ----
    f32x4 C1[8];
#pragma unroll
    for (int m = 0; m < 8; ++m) C1[m] = (f32x4){0.f, 0.f, 0.f, 0.f};
#pragma unroll
    for (int ks = 0; ks < 4; ++ks) {
        const int ncol = w * 16 + l15;
        const f16x8 bh = *(const f16x8*)(W1bt + (size_t)ncol * KP1 + lg * 8 + ks * 32);
#pragma unroll
        for (int m = 0; m < 8; ++m) {
            const int row = m * 16 + l15;
            const int byte = (lg * 16 + ks * 64) ^ ((row & 7) << 4);
            const f16x8 ah = *(const f16x8*)(sBig + row * 256 + byte);
            C1[m] = mfma16h(ah, bh, C1[m]);
        }
    }
    // per-seed colmax -> s_g (f32)
    {
        const int col = w * 16 + l15;
        const float bias = b1b[col];
        float pm0 = -INFINITY, pm1 = -INFINITY, pm2 = -INFINITY, pm3 = -INFINITY;
#pragma unroll
        for (int m = 0; m < 8; ++m)
#pragma unroll
            for (int r = 0; r < 4; ++r) {
                const float v = C1[m][r] + bias;
                if (m < 2)      pm0 = fmaxf(pm0, v);
                else if (m < 4) pm1 = fmaxf(pm1, v);
                else if (m < 6) pm2 = fmaxf(pm2, v);
                else            pm3 = fmaxf(pm3, v);
            }
        pm0 = fmaxf(pm0, __shfl_xor(pm0, 16)); pm0 = fmaxf(pm0, __shfl_xor(pm0, 32));
        pm1 = fmaxf(pm1, __shfl_xor(pm1, 16)); pm1 = fmaxf(pm1, __shfl_xor(pm1, 32));
        pm2 = fmaxf(pm2, __shfl_xor(pm2, 16)); pm2 = fmaxf(pm2, __shfl_xor(pm2, 32));
        pm3 = fmaxf(pm3, __shfl_xor(pm3, 16)); pm3 = fmaxf(pm3, __shfl_xor(pm3, 32));
        if (lg == 0) {
            s_g[0 * 256 + col] = pm0;
            s_g[1 * 256 + col] = pm1;
            s_g[2 * 256 + col] = pm2;
            s_g[3 * 256 + col] = pm3;
        }
    }
    __syncthreads();   // all h1 reads done; s_g complete

    // ---- A2 write: f -> f16 [128][512B] (overwrites dead h1) ----
    {
        const int col = w * 16 + l15;
        const float bias = b1b[col];
#pragma unroll
        for (int m = 0; m < 8; ++m)
#pragma unroll
            for (int r = 0; r < 4; ++r) {
                const float v = C1[m][r] + bias;
                const int row = m * 16 + lg * 4 + r;
                const int byte = (col * 2) ^ ((row & 7) << 4);
                *(_Float16*)(sBig + row * 512 + byte) = (_Float16)v;
            }
    }

    // ---- base[seed][c] = b2a[c] + g_seed @ W2a[0:256]; 2 seeds/thread ----
    {
        const int col = t & 511;
        const int sp  = t >> 9;                 // 0 -> seeds 0,1 ; 1 -> seeds 2,3
        float a0 = b2a[col], a1 = b2a[col];
        const float* g0 = s_g + (sp * 2) * 256;
        const float* g1 = s_g + (sp * 2 + 1) * 256;
#pragma unroll 4
        for (int jj = 0; jj < 256; ++jj) {
            const float w_ = W2a[(size_t)jj * 512 + col];
            a0 = fmaf(g0[jj], w_, a0);
            a1 = fmaf(g1[jj], w_, a1);
        }
        s_base[(sp * 2) * 512 + col]     = a0;
        s_base[(sp * 2 + 1) * 512 + col] = a1;
    }
    __syncthreads();   // A2 + s_base complete

    // ---- GEMM2: C2 = f @ W2a[256:] (M=128,N=512,K=256); cols w*32+n*16 ----
    f32x4 C2[8][2];
#pragma unroll
    for (int m = 0; m < 8; ++m)
#pragma unroll
        for (int n = 0; n < 2; ++n) C2[m][n] = (f32x4){0.f, 0.f, 0.f, 0.f};
#pragma unroll 2
    for (int ks = 0; ks < 8; ++ks) {
        f16x8 bh[2];
#pragma unroll
        for (int n = 0; n < 2; ++n) {
            const int ncol = w * 32 + n * 16 + l15;
            bh[n] = *(const f16x8*)(W2at + (size_t)ncol * KP2 + lg * 8 + ks * 32);
        }
#pragma unroll
        for (int m = 0; m < 8; ++m) {
            const int row = m * 16 + l15;
            const int byte = (lg * 16 + ks * 64) ^ ((row & 7) << 4);
            const f16x8 ah = *(const f16x8*)(sBig + row * 512 + byte);
            C2[m][0] = mfma16h(ah, bh[0], C2[m][0]);
            C2[m][1] = mfma16h(ah, bh[1], C2[m][1]);
        }
    }
    __syncthreads();   // A2 fully read; region reusable for A3

    // ---- A3 write: h2 = relu(C2 + base) -> f16 [128][1024B] ----
#pragma unroll
    for (int n = 0; n < 2; ++n) {
        const int col = w * 32 + n * 16 + l15;
#pragma unroll
        for (int m = 0; m < 8; ++m) {
            const float bs = s_base[(m >> 1) * 512 + col];
#pragma unroll
            for (int r = 0; r < 4; ++r) {
                const float v = fmaxf(C2[m][n][r] + bs, 0.0f);
                const int row = m * 16 + lg * 4 + r;
                const int byte = (col * 2) ^ ((row & 7) << 4);
                *(_Float16*)(sBig + row * 1024 + byte) = (_Float16)v;
            }
        }
    }
    __syncthreads();   // A3 complete

    // ---- GEMM3: e = h2 @ W2b (M=128,N=384,K=512); waves 0-11, no K-split ----
    if (w < 12) {
        f32x4 C3[8][2];
#pragma unroll
        for (int m = 0; m < 8; ++m)
#pragma unroll
            for (int n = 0; n < 2; ++n) C3[m][n] = (f32x4){0.f, 0.f, 0.f, 0.f};
#pragma unroll 2
        for (int ks = 0; ks < 16; ++ks) {
            f16x8 bh[2];
#pragma unroll
            for (int n = 0; n < 2; ++n) {
                const int ncol = w * 32 + n * 16 + l15;
                bh[n] = *(const f16x8*)(W2bt + (size_t)ncol * KP3 + lg * 8 + ks * 32);
            }
#pragma unroll
            for (int m = 0; m < 8; ++m) {
                const int row = m * 16 + l15;
                const int byte = (lg * 16 + ks * 64) ^ ((row & 7) << 4);
                const f16x8 ah = *(const f16x8*)(sBig + row * 1024 + byte);
                C3[m][0] = mfma16h(ah, bh[0], C3[m][0]);
                C3[m][1] = mfma16h(ah, bh[1], C3[m][1]);
            }
        }
        // epilogue: out[seed] = colmax(e_seed) + b2b
#pragma unroll
        for (int n = 0; n < 2; ++n) {
            const int col = w * 32 + n * 16 + l15;
            float pm0 = -INFINITY, pm1 = -INFINITY, pm2 = -INFINITY, pm3 = -INFINITY;
#pragma unroll
            for (int m = 0; m < 8; ++m)
#pragma unroll
                for (int r = 0; r < 4; ++r) {
                    const float v = C3[m][n][r];
                    if (m < 2)      pm0 = fmaxf(pm0, v);
                    else if (m < 4) pm1 = fmaxf(pm1, v);
                    else if (m < 6) pm2 = fmaxf(pm2, v);
                    else            pm3 = fmaxf(pm3, v);
                }
            pm0 = fmaxf(pm0, __shfl_xor(pm0, 16)); pm0 = fmaxf(pm0, __shfl_xor(pm0, 32));
            pm1 = fmaxf(pm1, __shfl_xor(pm1, 16)); pm1 = fmaxf(pm1, __shfl_xor(pm1, 32));
            pm2 = fmaxf(pm2, __shfl_xor(pm2, 16)); pm2 = fmaxf(pm2, __shfl_xor(pm2, 32));
            pm3 = fmaxf(pm3, __shfl_xor(pm3, 16)); pm3 = fmaxf(pm3, __shfl_xor(pm3, 32));
            if (lg == 0) {
                const float bb = b2b[col];
                out[(size_t)(blk * 4 + 0) * EMB + col] = pm0 + bb;
                out[(size_t)(blk * 4 + 1) * EMB + col] = pm1 + bb;
                out[(size_t)(blk * 4 + 2) * EMB + col] = pm2 + bb;
                out[(size_t)(blk * 4 + 3) * EMB + col] = pm3 + bb;
            }
        }
    }
}

// ---------------------------------------------------------------------------
extern "C" void kernel_launch(void* const* d_in, const int* in_sizes, int n_in,
                              void* d_out, int out_size, void* d_ws, size_t ws_size,
                              hipStream_t stream)
{
    const float* pos = (const float*)d_in[0];
    const float* W1a = (const float*)d_in[2];
    const float* b1a = (const float*)d_in[3];
    const float* W1b = (const float*)d_in[4];
    const float* b1b = (const float*)d_in[5];
    const float* W2a = (const float*)d_in[6];
    const float* b2a = (const float*)d_in[7];
    const float* W2b = (const float*)d_in[8];
    const float* b2b = (const float*)d_in[9];
    float* out = (float*)d_out;

    unsigned char* ws = (unsigned char*)d_ws;
    float* seed_pos = (float*)(ws + 0);                  // 12 KB
    int*   nbr      = (int*)(ws + 16384);                // 128 KB
    _Float16* W1bt  = (_Float16*)(ws + 147456);          // [256][136] 69632 B
    _Float16* W2at  = (_Float16*)(ws + 217088);          // [512][264] 270336 B
    _Float16* W2bt  = (_Float16*)(ws + 487424);          // [384][520] 399360 B

    pre_kernel<<<BB + 352, 256, 0, stream>>>(pos, seed_pos, W1b, W2a, W2b,
                                             W1bt, W2at, W2bt);
    knn_kernel<<<BB * SS / 8, 512, 0, stream>>>(pos, seed_pos, nbr);
    conv_kernel<<<BB * SS / 4, 1024, 0, stream>>>(pos, seed_pos, nbr,
                                                  W1a, b1a, b1b, W2a, b2a, b2b,
                                                  W1bt, W2at, W2bt, out);
}